// Round 15
// baseline (1245.568 us; speedup 1.0000x reference)
//
#include <hip/hip_runtime.h>
#include <stdint.h>

// Problem constants (n=1, c=32, h=w=128, p=3)
#define NPT    16384        // points (h*w)
#define KD     288          // c*p*p
#define KE     576          // per-point row: [hi(288) | lo(288)] f16
#define NWIN   9            // 9 K-windows of 32

typedef _Float16 f16;
typedef __attribute__((ext_vector_type(8))) _Float16 half8;
typedef __attribute__((ext_vector_type(4))) float floatx4;

// -------- patch extraction + fp32->2xf16 split + fused norms/init ------------
__global__ __launch_bounds__(256)
void extract_split_kernel(const float* __restrict__ src,
                          const float* __restrict__ tgt,
                          f16* __restrict__ Aext,
                          f16* __restrict__ Bext,
                          float* __restrict__ rq,
                          float* __restrict__ rp,
                          unsigned long long* __restrict__ best) {
  __shared__ f16 bufA[32 * KE];       // 36 KB
  __shared__ f16 bufB[32 * KE];       // 36 KB
  __shared__ double prtA[8][32];
  __shared__ double prtB[8][32];

  const int tid = threadIdx.x;
  const int p  = tid & 31;            // local point
  const int cg = tid >> 5;            // channel group 0..7
  const int point = blockIdx.x * 32 + p;
  const int y = point >> 7, x = point & 127;

  double sq = 0.0, sp_ = 0.0;
#pragma unroll
  for (int cc = 0; cc < 4; ++cc) {
    const int c = cg * 4 + cc;
#pragma unroll
    for (int dy = 0; dy < 3; ++dy) {
      int yy = y + dy - 1; yy = yy < 0 ? 0 : (yy > 127 ? 127 : yy);
#pragma unroll
      for (int dx = 0; dx < 3; ++dx) {
        int xx = x + dx - 1; xx = xx < 0 ? 0 : (xx > 127 ? 127 : xx);
        const int k = c * 9 + dy * 3 + dx;
        const int m = (c << 14) + (yy << 7) + xx;
        float v = src[m];
        sq += (double)v * (double)v;
        f16 h = (f16)v;
        bufA[p * KE + k] = h;
        bufA[p * KE + KD + k] = (f16)(v - (float)h);
        v = tgt[m];
        sp_ += (double)v * (double)v;
        h = (f16)v;
        bufB[p * KE + k] = h;
        bufB[p * KE + KD + k] = (f16)(v - (float)h);
      }
    }
  }
  prtA[cg][p] = sq;
  prtB[cg][p] = sp_;
  __syncthreads();

  if (tid < 32) {
    double s = 0.0;
#pragma unroll
    for (int g = 0; g < 8; ++g) s += prtA[g][tid];
    rq[blockIdx.x * 32 + tid] = (float)s;
    best[blockIdx.x * 32 + tid] = 0xFFFFFFFFFFFFFFFFULL;
  } else if (tid < 64) {
    double s = 0.0;
#pragma unroll
    for (int g = 0; g < 8; ++g) s += prtB[g][tid - 32];
    rp[blockIdx.x * 32 + (tid - 32)] = (float)s;
  }

  // coalesced wide stores: 2304 uint4 per matrix = 9 per thread
  const uint4* sA = (const uint4*)bufA;
  const uint4* sB = (const uint4*)bufB;
  uint4* gA = (uint4*)(Aext + (size_t)blockIdx.x * 32 * KE);
  uint4* gB = (uint4*)(Bext + (size_t)blockIdx.x * 32 * KE);
#pragma unroll
  for (int it = 0; it < 9; ++it) {
    gA[it * 256 + tid] = sA[it * 256 + tid];
    gB[it * 256 + tid] = sB[it * 256 + tid];
  }
}

// --- MFMA GEMM: LDS-free direct-fragment loads, zero barriers in K-loop ------
// Key insight: the 16x16x32 A/B fragment of lane l is a contiguous 16 B
// chunk of the row-major global array: row (tileBase + j*16 + (l&15)),
// k-octet (l>>4)*8 within the 32-half window at kw*32 (hi) / KD+kw*32 (lo).
// So fragments load straight from global (L2-resident via the supertile
// swizzle; B-slice per block ~L1-sized). No global_load_lds, no ds_read,
// no __syncthreads in the K-loop -> the compiler software-pipelines window
// kw+1's 16 loads under window kw's 48 MFMAs with fine-grained vmcnt — the
// overlap every barrier-based variant (r3/r9/r11/r14) could not express.
// LDS = 0 -> occupancy is VGPR-bound only.
__global__ __launch_bounds__(256)
void gemm_argmin_kernel(const f16* __restrict__ A, const f16* __restrict__ B,
                        const float* __restrict__ rq,
                        unsigned long long* __restrict__ best) {
  // ---- supertile swizzle: L -> (bx, by), 16x8 supertiles (r13: +8%) ----
  const int L  = blockIdx.x;          // 0..16383
  const int st = L >> 7;
  const int r  = L & 127;
  const int bx = ((st & 15) << 3) | (r & 7);
  const int by = ((st >> 4) << 4) | (r >> 3);

  const int nBase = bx * 128;
  const int mBase = by * 128;
  const int t = threadIdx.x;
  const int w = t >> 6;           // wave 0..3
  const int l = t & 63;

  // ---- fragment decode (16x16x32): lane reads 16 B at row*KE + q*8 ----
  const int m16 = l & 15;
  const int q   = l >> 4;                // k-octet 0..3
  const int wRow = (w & 1) * 64;
  const int wCol = (w >> 1) * 64;

  const f16* aP[4];
  const f16* bP[4];
#pragma unroll
  for (int i = 0; i < 4; ++i) {
    aP[i] = A + (size_t)(mBase + wRow + i * 16 + m16) * KE + q * 8;
    bP[i] = B + (size_t)(nBase + wCol + i * 16 + m16) * KE + q * 8;
  }

  floatx4 acc[4][4] = {};

#pragma unroll
  for (int kw = 0; kw < NWIN; ++kw) {
    // resident A fragments (hi + lo); window offset kw*32 halves = kw*64 B
    // and lo offset +KD are compile-time immediates per unrolled instance.
    half8 ah[4], al[4];
#pragma unroll
    for (int i = 0; i < 4; ++i) {
      ah[i] = *(const half8*)(aP[i] + kw * 32);
      al[i] = *(const half8*)(aP[i] + kw * 32 + KD);
    }
#pragma unroll
    for (int j = 0; j < 4; ++j) {
      half8 bh = *(const half8*)(bP[j] + kw * 32);
#pragma unroll
      for (int i = 0; i < 4; ++i)
        acc[i][j] = __builtin_amdgcn_mfma_f32_16x16x32_f16(ah[i], bh, acc[i][j], 0, 0, 0);
#pragma unroll
      for (int i = 0; i < 4; ++i)
        acc[i][j] = __builtin_amdgcn_mfma_f32_16x16x32_f16(al[i], bh, acc[i][j], 0, 0, 0);
    }
#pragma unroll
    for (int j = 0; j < 4; ++j) {
      half8 bl = *(const half8*)(bP[j] + kw * 32 + KD);
#pragma unroll
      for (int i = 0; i < 4; ++i)
        acc[i][j] = __builtin_amdgcn_mfma_f32_16x16x32_f16(ah[i], bl, acc[i][j], 0, 0, 0);
    }
  }

  // ---- epilogue: f = rq[col] - 2*dot, packed argmin ----
  // C/D layout (16x16): col = lane&15, row = (lane>>4)*4 + reg
  const int colBase = nBase + wCol + m16;
  float rqv[4];
#pragma unroll
  for (int j = 0; j < 4; ++j) rqv[j] = rq[colBase + j * 16];

#pragma unroll
  for (int i = 0; i < 4; ++i) {
    const int rowB = mBase + wRow + i * 16 + q * 4;
#pragma unroll
    for (int r2 = 0; r2 < 4; ++r2) {
      unsigned long long pk = 0xFFFFFFFFFFFFFFFFULL;
#pragma unroll
      for (int j = 0; j < 4; ++j) {
        float f = fmaf(-2.0f, acc[i][j][r2], rqv[j]);
        unsigned int bits = __float_as_uint(f);
        unsigned int key = (bits & 0x80000000u) ? ~bits : (bits | 0x80000000u);
        unsigned long long cand =
            ((unsigned long long)key << 32) | (unsigned)(colBase + j * 16);
        pk = pk < cand ? pk : cand;
      }
#pragma unroll
      for (int sft = 1; sft < 16; sft <<= 1) {
        unsigned long long o = __shfl_xor(pk, sft, 16);
        pk = pk < o ? pk : o;
      }
      if (m16 == 0) atomicMin(best + rowB + r2, pk);
    }
  }
}

// ---------------------------- finalize ---------------------------------------
__global__ void finalize_kernel(const unsigned long long* __restrict__ best,
                                const float* __restrict__ rp,
                                float* __restrict__ out) {
  int i = blockIdx.x * 256 + threadIdx.x;
  if (i >= NPT) return;
  unsigned long long v = best[i];
  unsigned int col = (unsigned int)(v & 0xFFFFFFFFu);
  unsigned int key = (unsigned int)(v >> 32);
  unsigned int bits = (key & 0x80000000u) ? (key & 0x7FFFFFFFu) : ~key;
  float fmin = __uint_as_float(bits);
  out[i]           = (float)(col >> 7);   // idy
  out[NPT + i]     = (float)(col & 127);  // idx
  out[2 * NPT + i] = rp[i] + fmin;        // nnd
}

extern "C" void kernel_launch(void* const* d_in, const int* in_sizes, int n_in,
                              void* d_out, int out_size, void* d_ws, size_t ws_size,
                              hipStream_t stream) {
  const float* src = (const float*)d_in[0];  // source_map (1,32,128,128)
  const float* tgt = (const float*)d_in[1];  // target_map (1,32,128,128)
  float* out = (float*)d_out;

  // workspace layout (bytes):
  //   Aext: [0, 18874368)        16384 x 576 f16 (point-major [hi|lo])
  //   Bext: [18874368, 37748736)
  //   rq  : [37748736, 37814272) 16384 fp32
  //   rp  : [37814272, 37879808)
  //   best: [37879808, 38010880) 16384 u64 packed (key<<32)|col
  char* ws = (char*)d_ws;
  f16* Aext = (f16*)(ws);
  f16* Bext = (f16*)(ws + 18874368);
  float* rq = (float*)(ws + 37748736);
  float* rp = (float*)(ws + 37814272);
  unsigned long long* best = (unsigned long long*)(ws + 37879808);

  extract_split_kernel<<<NPT / 32, 256, 0, stream>>>(src, tgt, Aext, Bext,
                                                     rq, rp, best);
  gemm_argmin_kernel<<<16384, 256, 0, stream>>>(Aext, Bext, rq, best);
  finalize_kernel<<<NPT / 256, 256, 0, stream>>>(best, rp, out);
}

// Round 16
// 548.248 us; speedup vs baseline: 2.2719x; 2.2719x over previous
//
#include <hip/hip_runtime.h>
#include <stdint.h>

// Problem constants (n=1, c=32, h=w=128, p=3)
#define NPT    16384        // points (h*w)
#define KD     288          // c*p*p
#define KE     576          // per-point row: [hi(288) | lo(288)] f16
#define NWIN   9            // 9 merged K-windows of 32 (hi+lo staged together)

typedef _Float16 f16;
typedef __attribute__((ext_vector_type(8))) _Float16 half8;
typedef __attribute__((ext_vector_type(4))) float floatx4;

#define AS1(p) ((const __attribute__((address_space(1))) uint32_t*)(p))
#define AS3(p) ((__attribute__((address_space(3))) uint32_t*)(p))

// -------- patch extraction + fp32->2xf16 split + fused norms/init ------------
__global__ __launch_bounds__(256)
void extract_split_kernel(const float* __restrict__ src,
                          const float* __restrict__ tgt,
                          f16* __restrict__ Aext,
                          f16* __restrict__ Bext,
                          float* __restrict__ rq,
                          float* __restrict__ rp,
                          unsigned long long* __restrict__ best) {
  __shared__ f16 bufA[32 * KE];       // 36 KB
  __shared__ f16 bufB[32 * KE];       // 36 KB
  __shared__ double prtA[8][32];
  __shared__ double prtB[8][32];

  const int tid = threadIdx.x;
  const int p  = tid & 31;            // local point
  const int cg = tid >> 5;            // channel group 0..7
  const int point = blockIdx.x * 32 + p;
  const int y = point >> 7, x = point & 127;

  double sq = 0.0, sp_ = 0.0;
#pragma unroll
  for (int cc = 0; cc < 4; ++cc) {
    const int c = cg * 4 + cc;
#pragma unroll
    for (int dy = 0; dy < 3; ++dy) {
      int yy = y + dy - 1; yy = yy < 0 ? 0 : (yy > 127 ? 127 : yy);
#pragma unroll
      for (int dx = 0; dx < 3; ++dx) {
        int xx = x + dx - 1; xx = xx < 0 ? 0 : (xx > 127 ? 127 : xx);
        const int k = c * 9 + dy * 3 + dx;
        const int m = (c << 14) + (yy << 7) + xx;
        float v = src[m];
        sq += (double)v * (double)v;
        f16 h = (f16)v;
        bufA[p * KE + k] = h;
        bufA[p * KE + KD + k] = (f16)(v - (float)h);
        v = tgt[m];
        sp_ += (double)v * (double)v;
        h = (f16)v;
        bufB[p * KE + k] = h;
        bufB[p * KE + KD + k] = (f16)(v - (float)h);
      }
    }
  }
  prtA[cg][p] = sq;
  prtB[cg][p] = sp_;
  __syncthreads();

  if (tid < 32) {
    double s = 0.0;
#pragma unroll
    for (int g = 0; g < 8; ++g) s += prtA[g][tid];
    rq[blockIdx.x * 32 + tid] = (float)s;
    best[blockIdx.x * 32 + tid] = 0xFFFFFFFFFFFFFFFFULL;
  } else if (tid < 64) {
    double s = 0.0;
#pragma unroll
    for (int g = 0; g < 8; ++g) s += prtB[g][tid - 32];
    rp[blockIdx.x * 32 + (tid - 32)] = (float)s;
  }

  // coalesced wide stores: 2304 uint4 per matrix = 9 per thread
  const uint4* sA = (const uint4*)bufA;
  const uint4* sB = (const uint4*)bufB;
  uint4* gA = (uint4*)(Aext + (size_t)blockIdx.x * 32 * KE);
  uint4* gB = (uint4*)(Bext + (size_t)blockIdx.x * 32 * KE);
#pragma unroll
  for (int it = 0; it < 9; ++it) {
    gA[it * 256 + tid] = sA[it * 256 + tid];
    gB[it * 256 + tid] = sB[it * 256 + tid];
  }
}

// --- MFMA GEMM: 256x128 block tile (512 thr, 8 waves), window amortization ---
// vs r13 (128x128): half the barrier-drain events per CU, 25% less staging
// traffic per FLOP, SAME 16 waves/CU residency (LDS 48 KB -> 3 blocks by LDS;
// VGPR forced <=128 via (512,4), the budget r12 measured to fit the slim
// fragment plan). Same measured-0-conflict swizzle, same 16x16x32 path.
// Supertile swizzle: 64-block supertiles (8 bx x 8 by); consecutive blocks
// round-robin XCDs -> XCD k gets 1 B-tile (288 KB) + 8 A-tiles (2.36 MB)
// = 2.6 MB < 4 MiB L2 (r13: +8% from L2-resident staging).
__global__ __launch_bounds__(512, 4)
void gemm_argmin_kernel(const f16* __restrict__ A, const f16* __restrict__ B,
                        const float* __restrict__ rq,
                        unsigned long long* __restrict__ best) {
  __shared__ f16 Ash[256 * 64];   // 32 KB
  __shared__ f16 Bsh[128 * 64];   // 16 KB

  // ---- supertile swizzle: L -> (bx, by); bx 0..127 (N), by 0..63 (M) ----
  const int L  = blockIdx.x;          // 0..8191
  const int st = L >> 6;              // supertile 0..127
  const int r  = L & 63;
  const int bx = ((st & 15) << 3) | (r & 7);     // 0..127
  const int by = ((st >> 4) << 3) | (r >> 3);    // 0..63

  const int nBase = bx * 128;
  const int mBase = by * 256;
  const f16* Ab = A + (size_t)mBase * KE;   // block-uniform -> SGPR pair
  const f16* Bb = B + (size_t)nBase * KE;
  const int t = threadIdx.x;
  const int w = t >> 6;           // wave 0..7
  const int l = t & 63;

  // ---- staging decode: per issue, 64 lanes cover 8 rows x 8 phys slots ----
  const int lr = l >> 3;                 // row within 8-row issue group
  const int lt = l & 7;                  // phys 16B slot
  const int sl = lt ^ (lr & 7);          // logical slice this lane fetches
  const int sColOff = (sl < 4) ? sl * 8 : KD + (sl & 3) * 8;  // + kw*32/window
  int aRow[4], bRow[2];
#pragma unroll
  for (int ig = 0; ig < 4; ++ig)
    aRow[ig] = (w * 32 + ig * 8 + lr) * KE + sColOff;   // A rows 0..255
#pragma unroll
  for (int ig = 0; ig < 2; ++ig)
    bRow[ig] = (w * 16 + ig * 8 + lr) * KE + sColOff;   // B rows 0..127

  // ---- fragment decode (16x16x32) ----
  const int m16 = l & 15;
  const int q   = l >> 4;                // k-quad
  const int pHi = q ^ (m16 & 7);         // phys slot of hi octet q
  const int pLo = pHi ^ 4;               // phys slot of lo octet q
  const int wRow = (w & 3) * 64;         // 4 row groups over 256
  const int wCol = (w >> 2) * 64;        // 2 col groups over 128
  const int aHiOff = m16 * 64 + pHi * 8;
  const int aLoOff = m16 * 64 + pLo * 8;

  floatx4 acc[4][4] = {};

#pragma unroll
  for (int kw = 0; kw < NWIN; ++kw) {
    __syncthreads();                     // previous window's reads complete
#pragma unroll
    for (int ig = 0; ig < 4; ++ig)
      __builtin_amdgcn_global_load_lds(AS1(Ab + aRow[ig] + kw * 32),
                                       AS3(&Ash[(w * 32 + ig * 8) * 64]), 16, 0, 0);
#pragma unroll
    for (int ig = 0; ig < 2; ++ig)
      __builtin_amdgcn_global_load_lds(AS1(Bb + bRow[ig] + kw * 32),
                                       AS3(&Bsh[(w * 16 + ig * 8) * 64]), 16, 0, 0);
    __syncthreads();                     // staging drained

    // resident A fragments (hi + lo); stream B fragments one tile at a time
    half8 ah[4], al[4];
#pragma unroll
    for (int i = 0; i < 4; ++i) {
      ah[i] = *(const half8*)&Ash[(wRow + i * 16) * 64 + aHiOff];
      al[i] = *(const half8*)&Ash[(wRow + i * 16) * 64 + aLoOff];
    }
#pragma unroll
    for (int j = 0; j < 4; ++j) {
      half8 bh = *(const half8*)&Bsh[(wCol + j * 16) * 64 + aHiOff];
#pragma unroll
      for (int i = 0; i < 4; ++i)
        acc[i][j] = __builtin_amdgcn_mfma_f32_16x16x32_f16(ah[i], bh, acc[i][j], 0, 0, 0);
#pragma unroll
      for (int i = 0; i < 4; ++i)
        acc[i][j] = __builtin_amdgcn_mfma_f32_16x16x32_f16(al[i], bh, acc[i][j], 0, 0, 0);
    }
#pragma unroll
    for (int j = 0; j < 4; ++j) {
      half8 bl = *(const half8*)&Bsh[(wCol + j * 16) * 64 + aLoOff];
#pragma unroll
      for (int i = 0; i < 4; ++i)
        acc[i][j] = __builtin_amdgcn_mfma_f32_16x16x32_f16(ah[i], bl, acc[i][j], 0, 0, 0);
    }
  }

  // ---- epilogue: f = rq[col] - 2*dot, packed argmin ----
  // C/D layout (16x16): col = lane&15, row = (lane>>4)*4 + reg
  const int colBase = nBase + wCol + m16;
  float rqv[4];
#pragma unroll
  for (int j = 0; j < 4; ++j) rqv[j] = rq[colBase + j * 16];

#pragma unroll
  for (int i = 0; i < 4; ++i) {
    const int rowB = mBase + wRow + i * 16 + q * 4;
#pragma unroll
    for (int r2 = 0; r2 < 4; ++r2) {
      unsigned long long pk = 0xFFFFFFFFFFFFFFFFULL;
#pragma unroll
      for (int j = 0; j < 4; ++j) {
        float f = fmaf(-2.0f, acc[i][j][r2], rqv[j]);
        unsigned int bits = __float_as_uint(f);
        unsigned int key = (bits & 0x80000000u) ? ~bits : (bits | 0x80000000u);
        unsigned long long cand =
            ((unsigned long long)key << 32) | (unsigned)(colBase + j * 16);
        pk = pk < cand ? pk : cand;
      }
#pragma unroll
      for (int sft = 1; sft < 16; sft <<= 1) {
        unsigned long long o = __shfl_xor(pk, sft, 16);
        pk = pk < o ? pk : o;
      }
      if (m16 == 0) atomicMin(best + rowB + r2, pk);
    }
  }
}

// ---------------------------- finalize ---------------------------------------
__global__ void finalize_kernel(const unsigned long long* __restrict__ best,
                                const float* __restrict__ rp,
                                float* __restrict__ out) {
  int i = blockIdx.x * 256 + threadIdx.x;
  if (i >= NPT) return;
  unsigned long long v = best[i];
  unsigned int col = (unsigned int)(v & 0xFFFFFFFFu);
  unsigned int key = (unsigned int)(v >> 32);
  unsigned int bits = (key & 0x80000000u) ? (key & 0x7FFFFFFFu) : ~key;
  float fmin = __uint_as_float(bits);
  out[i]           = (float)(col >> 7);   // idy
  out[NPT + i]     = (float)(col & 127);  // idx
  out[2 * NPT + i] = rp[i] + fmin;        // nnd
}

extern "C" void kernel_launch(void* const* d_in, const int* in_sizes, int n_in,
                              void* d_out, int out_size, void* d_ws, size_t ws_size,
                              hipStream_t stream) {
  const float* src = (const float*)d_in[0];  // source_map (1,32,128,128)
  const float* tgt = (const float*)d_in[1];  // target_map (1,32,128,128)
  float* out = (float*)d_out;

  // workspace layout (bytes):
  //   Aext: [0, 18874368)        16384 x 576 f16 (point-major [hi|lo])
  //   Bext: [18874368, 37748736)
  //   rq  : [37748736, 37814272) 16384 fp32
  //   rp  : [37814272, 37879808)
  //   best: [37879808, 38010880) 16384 u64 packed (key<<32)|col
  char* ws = (char*)d_ws;
  f16* Aext = (f16*)(ws);
  f16* Bext = (f16*)(ws + 18874368);
  float* rq = (float*)(ws + 37748736);
  float* rp = (float*)(ws + 37814272);
  unsigned long long* best = (unsigned long long*)(ws + 37879808);

  extract_split_kernel<<<NPT / 32, 256, 0, stream>>>(src, tgt, Aext, Bext,
                                                     rq, rp, best);
  gemm_argmin_kernel<<<8192, 512, 0, stream>>>(Aext, Bext, rq, best);
  finalize_kernel<<<NPT / 256, 256, 0, stream>>>(best, rp, out);
}